// Round 15
// baseline (38.199 us; speedup 1.0000x reference)
//
#include <hip/hip_runtime.h>
#include <math.h>

#define NC     10
#define NCP    12     // padded row stride (floats); 48B rows, 16B aligned
#define NM     128
#define NGEN   4
#define NPT    1023
#define NTREES 1024

// ws layout (floats): ac[4][10][12] | pi[4][12] | bt[4][128][12]
#define WS_AC(g)   ((g) * (NC * NCP))
#define WS_PI(g)   (4 * NC * NCP + (g) * NCP)
#define WS_BT(g)   (4 * NC * NCP + 4 * NCP + (g) * (NM * NCP))
#define WS_FLOATS  (4 * NC * NCP + 4 * NCP + 4 * NM * NCP)

#define RCPF(x) __builtin_amdgcn_rcpf(x)
#define WAVE_FENCE() __builtin_amdgcn_wave_barrier()

struct F12 { float4 a, b, c; };

__device__ __forceinline__ F12 ld12(const float* p) {
    F12 r; const float4* q = (const float4*)p;
    r.a = q[0]; r.b = q[1]; r.c = q[2]; return r;
}
__device__ __forceinline__ void unpack10(float* t, const F12& r) {
    t[0] = r.a.x; t[1] = r.a.y; t[2] = r.a.z; t[3] = r.a.w;
    t[4] = r.b.x; t[5] = r.b.y; t[6] = r.b.z; t[7] = r.b.w;
    t[8] = r.c.x; t[9] = r.c.y;
}
__device__ __forceinline__ void fma10(float* t, const F12& c, float s) {
    t[0] += c.a.x * s; t[1] += c.a.y * s; t[2] += c.a.z * s; t[3] += c.a.w * s;
    t[4] += c.b.x * s; t[5] += c.b.y * s; t[6] += c.b.z * s; t[7] += c.b.w * s;
    t[8] += c.c.x * s; t[9] += c.c.y * s;
}
__device__ __forceinline__ void mul10(float* t, const F12& r) {
    t[0] *= r.a.x; t[1] *= r.a.y; t[2] *= r.a.z; t[3] *= r.a.w;
    t[4] *= r.b.x; t[5] *= r.b.y; t[6] *= r.b.z; t[7] *= r.b.w;
    t[8] *= r.c.x; t[9] *= r.c.y;
}
__device__ __forceinline__ float sum10(const float* v) {
    return (((v[0] + v[1]) + (v[2] + v[3])) + ((v[4] + v[5]) + (v[6] + v[7]))) + (v[8] + v[9]);
}

// 7-node telescoped half-subtree {4 leaves, 2 L8 unnorm, L7}: 1 log + 1 rcp.
// Leaves: sBT row scaled by piv from registers (sBTpi table eliminated).
__device__ __forceinline__ float half_subtree(const F12* acol,
                                              const float (*sBT)[NCP],
                                              const float* piv,
                                              int xl0, int xl1, int xl2, int xl3,
                                              int x8a, int x8b, int x7, float* b7out)
{
    float b0[NC], b1[NC], sc[NC], t8a[NC], t8b[NC];

    unpack10(b0, ld12(&sBT[xl0][0]));
    unpack10(b1, ld12(&sBT[xl1][0]));
    #pragma unroll
    for (int j = 0; j < NC; ++j) { b0[j] *= piv[j]; b1[j] *= piv[j]; }
    float nu0 = sum10(b0), nu1 = sum10(b1);
    #pragma unroll
    for (int j = 0; j < NC; ++j) sc[j] = b0[j] * nu1 + b1[j] * nu0;
    #pragma unroll
    for (int i = 0; i < NC; ++i) t8a[i] = 0.f;
    #pragma unroll
    for (int j = 0; j < NC; ++j) fma10(t8a, acol[j], sc[j]);
    mul10(t8a, ld12(&sBT[x8a][0]));
    const float nu8a = sum10(t8a);

    unpack10(b0, ld12(&sBT[xl2][0]));
    unpack10(b1, ld12(&sBT[xl3][0]));
    #pragma unroll
    for (int j = 0; j < NC; ++j) { b0[j] *= piv[j]; b1[j] *= piv[j]; }
    nu0 = sum10(b0); nu1 = sum10(b1);
    #pragma unroll
    for (int j = 0; j < NC; ++j) sc[j] = b0[j] * nu1 + b1[j] * nu0;
    #pragma unroll
    for (int i = 0; i < NC; ++i) t8b[i] = 0.f;
    #pragma unroll
    for (int j = 0; j < NC; ++j) fma10(t8b, acol[j], sc[j]);
    mul10(t8b, ld12(&sBT[x8b][0]));
    const float nu8b = sum10(t8b);

    #pragma unroll
    for (int j = 0; j < NC; ++j) sc[j] = t8a[j] * nu8b + t8b[j] * nu8a;
    float t7[NC];
    #pragma unroll
    for (int i = 0; i < NC; ++i) t7[i] = 0.f;
    #pragma unroll
    for (int j = 0; j < NC; ++j) fma10(t7, acol[j], sc[j]);
    mul10(t7, ld12(&sBT[x7][0]));
    const float nu7 = sum10(t7);
    const float r = RCPF(nu7);
    #pragma unroll
    for (int j = 0; j < NC; ++j) b7out[j] = t7[j] * r;
    return __logf(nu7);
}

// fused 2-level tail step, in place (stride 64), telescoped (1 log, 1 rcp).
__device__ __forceinline__ float fused_step_ip(const F12* acol, const float (*sBT)[NCP],
                                               float* buf, int l,
                                               int xc0, int xc1, int xp)
{
    float t0[NC], t1[NC];
    #pragma unroll
    for (int i = 0; i < NC; ++i) { t0[i] = 0.f; t1[i] = 0.f; }
    #pragma unroll
    for (int j = 0; j < NC; ++j) {
        float4 gv = *(const float4*)(buf + j * 64 + 4 * l);
        fma10(t0, acol[j], gv.x + gv.y);
        fma10(t1, acol[j], gv.z + gv.w);
    }
    mul10(t0, ld12(&sBT[xc0][0]));
    mul10(t1, ld12(&sBT[xc1][0]));
    const float nu0 = sum10(t0), nu1 = sum10(t1);
    float tp[NC];
    #pragma unroll
    for (int i = 0; i < NC; ++i) tp[i] = 0.f;
    #pragma unroll
    for (int j = 0; j < NC; ++j) fma10(tp, acol[j], t0[j] * nu1 + t1[j] * nu0);
    mul10(tp, ld12(&sBT[xp][0]));
    const float nup = sum10(tp);
    const float rp = RCPF(nup);
    #pragma unroll
    for (int j = 0; j < NC; ++j) buf[j * 64 + l] = tp[j] * rp;
    return __logf(nup);
}

// ---------------- kernel 0: softmax tables into ws (4 blocks, once) --------
__global__ __launch_bounds__(128)
void htmm_setup(const float* __restrict__ A,
                const float* __restrict__ B,
                const float* __restrict__ Pi,
                float* __restrict__ ws)
{
    const int g = blockIdx.x;
    const int tid = threadIdx.x;
    const int wave = tid >> 6, lane = tid & 63;
    float* bt = ws + WS_BT(g);

    // B row softmax over m (no-max: |2.5*N| small, exp safe — R11-validated)
    for (int c = wave; c < NC; c += 2) {
        float e0 = __expf(B[(c * NM + lane) * NGEN + g]);
        float e1 = __expf(B[(c * NM + lane + 64) * NGEN + g]);
        float s = e0 + e1;
        #pragma unroll
        for (int off = 32; off; off >>= 1) s += __shfl_xor(s, off);
        const float rs = 1.f / s;
        bt[lane * NCP + c]        = e0 * rs;
        bt[(lane + 64) * NCP + c] = e1 * rs;
    }
    if (tid < NM) { bt[tid * NCP + 10] = 0.f; bt[tid * NCP + 11] = 0.f; }

    if (tid < NC) {   // A column softmax, 0.5 folded, col-major rows of 12
        const int j = tid;
        float col[NC], mx = -1e30f;
        #pragma unroll
        for (int i = 0; i < NC; ++i) { col[i] = A[(i * NC + j) * NGEN + g]; mx = fmaxf(mx, col[i]); }
        float s = 0.f;
        #pragma unroll
        for (int i = 0; i < NC; ++i) { col[i] = __expf(col[i] - mx); s += col[i]; }
        const float rs = 0.5f / s;
        float* ac = ws + WS_AC(g) + j * NCP;
        #pragma unroll
        for (int i = 0; i < NC; ++i) ac[i] = col[i] * rs;
        ac[10] = 0.f; ac[11] = 0.f;
    }
    if (tid == 32) {  // Pi softmax
        float col[NC], mx = -1e30f;
        #pragma unroll
        for (int i = 0; i < NC; ++i) { col[i] = Pi[i * NGEN + g]; mx = fmaxf(mx, col[i]); }
        float s = 0.f;
        #pragma unroll
        for (int i = 0; i < NC; ++i) { col[i] = __expf(col[i] - mx); s += col[i]; }
        const float rs = 1.f / s;
        float* pp = ws + WS_PI(g);
        #pragma unroll
        for (int i = 0; i < NC; ++i) pp[i] = col[i] * rs;
        pp[10] = 0.f; pp[11] = 0.f;
    }
}

// ---------------- kernel 1: main — 4096 independent 1-wave blocks -----------
// One (tree,g) unit per block. Block copies the 6KB B-table into LDS (12
// vector insts), A/pi live in registers from uniform L2-hit loads. Zero
// __syncthreads. 16 blocks/CU co-resident (LDS 8.7KB, VGPR-tier 4 waves/SIMD)
// -> finest scheduling granularity (R13 showed 9.3% occupancy at 4 big
// blocks/CU = CU starvation). Gathers stay in LDS (R10: global gathers lose).
__global__ __launch_bounds__(64)
void htmm_main(const int* __restrict__ x,
               const float* __restrict__ ws,
               float* __restrict__ out)
{
    __shared__ __align__(16) float sBT[NM][NCP];   // 6144 B
    __shared__ __align__(16) float sB6[NC][64];    // 2560 B; tail in place

    const int bid  = blockIdx.x;
    const int tree = bid >> 2;
    const int g    = bid & 3;
    const int lane = threadIdx.x;
    const int tb   = tree * NPT;

    // issue the table copy loads first (latency overlaps everything below)
    const float4* src = (const float4*)(ws + WS_BT(g));
    float4 cp0 = src[0 * 64 + lane], cp1 = src[1 * 64 + lane];
    float4 cp2 = src[2 * 64 + lane], cp3 = src[3 * 64 + lane];
    float4 cp4 = src[4 * 64 + lane], cp5 = src[5 * 64 + lane];

    // observation indices for this lane's subtree
    int xl[8];
    #pragma unroll
    for (int k = 0; k < 8; ++k) xl[k] = x[tb + 511 + 8 * lane + k];
    int x8v[4];
    #pragma unroll
    for (int c = 0; c < 4; ++c) x8v[c] = x[tb + 255 + 4 * lane + c];
    const int x7a = x[tb + 127 + 2 * lane];
    const int x7b = x[tb + 128 + 2 * lane];
    const int x6v = x[tb + 63 + lane];

    // A columns + pi into registers (wave-uniform loads, L2-hit)
    F12 acol[NC];
    #pragma unroll
    for (int j = 0; j < NC; ++j) acol[j] = ld12(ws + WS_AC(g) + j * NCP);
    float piv[NC];
    { F12 pv = ld12(ws + WS_PI(g)); unpack10(piv, pv); }

    // land the table in LDS (wave-local; DS in-order per wave)
    {
        float4* dst = (float4*)&sBT[0][0];
        dst[0 * 64 + lane] = cp0; dst[1 * 64 + lane] = cp1;
        dst[2 * 64 + lane] = cp2; dst[3 * 64 + lane] = cp3;
        dst[4 * 64 + lane] = cp4; dst[5 * 64 + lane] = cp5;
    }
    WAVE_FENCE();

    // ---- head: two telescoped halves, then L6 ----
    float b7a[NC], b7b[NC];
    float llacc;
    llacc  = half_subtree(acol, sBT, piv, xl[0], xl[1], xl[2], xl[3],
                          x8v[0], x8v[1], x7a, b7a);
    llacc += half_subtree(acol, sBT, piv, xl[4], xl[5], xl[6], xl[7],
                          x8v[2], x8v[3], x7b, b7b);
    {
        float sc[NC], t6[NC];
        #pragma unroll
        for (int j = 0; j < NC; ++j) sc[j] = b7a[j] + b7b[j];
        #pragma unroll
        for (int i = 0; i < NC; ++i) t6[i] = 0.f;
        #pragma unroll
        for (int j = 0; j < NC; ++j) fma10(t6, acol[j], sc[j]);
        mul10(t6, ld12(&sBT[x6v][0]));
        const float nup = sum10(t6);
        llacc += __logf(nup);
        const float rp = RCPF(nup);
        #pragma unroll
        for (int j = 0; j < NC; ++j) sB6[j][lane] = t6[j] * rp;
    }

    // ---- tail: levels 5..0, wave-local, in place ----
    WAVE_FENCE();
    float lla = 0.f;
    if (lane < 16)
        lla = fused_step_ip(acol, sBT, &sB6[0][0], lane,
                            x[tb + 31 + 2 * lane], x[tb + 32 + 2 * lane],
                            x[tb + 15 + lane]);
    llacc += lla;
    WAVE_FENCE();
    float llb = 0.f;
    if (lane < 4)
        llb = fused_step_ip(acol, sBT, &sB6[0][0], lane,
                            x[tb + 7 + 2 * lane], x[tb + 8 + 2 * lane],
                            x[tb + 3 + lane]);
    llacc += llb;
    WAVE_FENCE();
    if (lane == 0)
        llacc += fused_step_ip(acol, sBT, &sB6[0][0], 0,
                               x[tb + 1], x[tb + 2], x[tb + 0]);

    #pragma unroll
    for (int off = 32; off; off >>= 1) llacc += __shfl_down(llacc, off);
    if (lane == 0) out[tree * NGEN + g] = llacc;
}

// ---------------- fallback: R14 monolithic (known-good, 26.7 µs) ------------
__global__ __launch_bounds__(256)
void htmm_fused(const int* __restrict__ x,
                const float* __restrict__ A,
                const float* __restrict__ B,
                const float* __restrict__ Pi,
                float* __restrict__ out)
{
    __shared__ __align__(16) float sACol[NC][NCP];
    __shared__ __align__(16) float sBT[NM][NCP];
    __shared__ __align__(16) float sBTpi[NM][NCP];
    __shared__ __align__(16) float sB6[4][NC][64];

    const int bid = blockIdx.x;
    const int g = bid >> 8;
    const int treeBase = (bid & 255) * 4;
    const int tid = threadIdx.x;
    const int u = tid >> 6, lane = tid & 63;
    const int tree = treeBase + u;
    const int tb = tree * NPT;

    int xl[8];
    #pragma unroll
    for (int k = 0; k < 8; ++k) xl[k] = x[tb + 511 + 8 * lane + k];
    int x8v[4];
    #pragma unroll
    for (int c = 0; c < 4; ++c) x8v[c] = x[tb + 255 + 4 * lane + c];
    const int x7a = x[tb + 127 + 2 * lane];
    const int x7b = x[tb + 128 + 2 * lane];
    const int x6v = x[tb + 63 + lane];

    float piv[NC];
    {
        float mx = -1e30f;
        #pragma unroll
        for (int i = 0; i < NC; ++i) { piv[i] = Pi[i * NGEN + g]; mx = fmaxf(mx, piv[i]); }
        float sm = 0.f;
        #pragma unroll
        for (int i = 0; i < NC; ++i) { piv[i] = __expf(piv[i] - mx); sm += piv[i]; }
        const float rs = 1.f / sm;
        #pragma unroll
        for (int i = 0; i < NC; ++i) piv[i] *= rs;
    }
    for (int c = u; c < NC; c += 4) {
        float e0 = __expf(B[(c * NM + lane) * NGEN + g]);
        float e1 = __expf(B[(c * NM + lane + 64) * NGEN + g]);
        float sm = e0 + e1;
        #pragma unroll
        for (int off = 32; off; off >>= 1) sm += __shfl_xor(sm, off);
        const float rs = 1.f / sm;
        const float v0 = e0 * rs, v1 = e1 * rs;
        sBT[lane][c]        = v0;
        sBT[lane + 64][c]   = v1;
        sBTpi[lane][c]      = piv[c] * v0;
        sBTpi[lane + 64][c] = piv[c] * v1;
    }
    if (tid >= 128 && tid < 128 + NC) {
        const int j = tid - 128;
        float col[NC], mx = -1e30f;
        #pragma unroll
        for (int i = 0; i < NC; ++i) { col[i] = A[(i * NC + j) * NGEN + g]; mx = fmaxf(mx, col[i]); }
        float sm = 0.f;
        #pragma unroll
        for (int i = 0; i < NC; ++i) { col[i] = __expf(col[i] - mx); sm += col[i]; }
        const float rs = 0.5f / sm;
        #pragma unroll
        for (int i = 0; i < NC; ++i) sACol[j][i] = col[i] * rs;
    }
    __syncthreads();

    F12 acol[NC];
    #pragma unroll
    for (int j = 0; j < NC; ++j) acol[j] = ld12(&sACol[j][0]);

    float ones[NC];
    #pragma unroll
    for (int i = 0; i < NC; ++i) ones[i] = 1.f;

    float b7a[NC], b7b[NC];
    float llacc;
    // reuse half_subtree with piv=1 against sBTpi-preloaded leaves:
    llacc  = half_subtree(acol, sBT, ones, 0, 0, 0, 0, 0, 0, 0, b7a);  // placeholder never used
    llacc = 0.f;
    {   // inline halves using sBTpi (original R14 path)
        float b0[NC], b1[NC], sc[NC], t8a[NC], t8b[NC];
        #pragma unroll
        for (int h = 0; h < 2; ++h) {
            const int* xh = xl + 4 * h;
            const int x8a = x8v[2 * h], x8b = x8v[2 * h + 1];
            const int x7 = h ? x7b : x7a;
            unpack10(b0, ld12(&sBTpi[xh[0]][0]));
            unpack10(b1, ld12(&sBTpi[xh[1]][0]));
            float nu0 = sum10(b0), nu1 = sum10(b1);
            #pragma unroll
            for (int j = 0; j < NC; ++j) sc[j] = b0[j] * nu1 + b1[j] * nu0;
            #pragma unroll
            for (int i = 0; i < NC; ++i) t8a[i] = 0.f;
            #pragma unroll
            for (int j = 0; j < NC; ++j) fma10(t8a, acol[j], sc[j]);
            mul10(t8a, ld12(&sBT[x8a][0]));
            const float nu8a = sum10(t8a);
            unpack10(b0, ld12(&sBTpi[xh[2]][0]));
            unpack10(b1, ld12(&sBTpi[xh[3]][0]));
            nu0 = sum10(b0); nu1 = sum10(b1);
            #pragma unroll
            for (int j = 0; j < NC; ++j) sc[j] = b0[j] * nu1 + b1[j] * nu0;
            #pragma unroll
            for (int i = 0; i < NC; ++i) t8b[i] = 0.f;
            #pragma unroll
            for (int j = 0; j < NC; ++j) fma10(t8b, acol[j], sc[j]);
            mul10(t8b, ld12(&sBT[x8b][0]));
            const float nu8b = sum10(t8b);
            #pragma unroll
            for (int j = 0; j < NC; ++j) sc[j] = t8a[j] * nu8b + t8b[j] * nu8a;
            float t7[NC];
            #pragma unroll
            for (int i = 0; i < NC; ++i) t7[i] = 0.f;
            #pragma unroll
            for (int j = 0; j < NC; ++j) fma10(t7, acol[j], sc[j]);
            mul10(t7, ld12(&sBT[x7][0]));
            const float nu7 = sum10(t7);
            const float r = RCPF(nu7);
            float* dst = h ? b7b : b7a;
            #pragma unroll
            for (int j = 0; j < NC; ++j) dst[j] = t7[j] * r;
            llacc += __logf(nu7);
        }
    }
    {
        float sc[NC], t6[NC];
        #pragma unroll
        for (int j = 0; j < NC; ++j) sc[j] = b7a[j] + b7b[j];
        #pragma unroll
        for (int i = 0; i < NC; ++i) t6[i] = 0.f;
        #pragma unroll
        for (int j = 0; j < NC; ++j) fma10(t6, acol[j], sc[j]);
        mul10(t6, ld12(&sBT[x6v][0]));
        const float nup = sum10(t6);
        llacc += __logf(nup);
        const float rp = RCPF(nup);
        #pragma unroll
        for (int j = 0; j < NC; ++j) sB6[u][j][lane] = t6[j] * rp;
    }

    WAVE_FENCE();
    float lla = 0.f;
    if (lane < 16)
        lla = fused_step_ip(acol, sBT, &sB6[u][0][0], lane,
                            x[tb + 31 + 2 * lane], x[tb + 32 + 2 * lane],
                            x[tb + 15 + lane]);
    llacc += lla;
    WAVE_FENCE();
    float llb = 0.f;
    if (lane < 4)
        llb = fused_step_ip(acol, sBT, &sB6[u][0][0], lane,
                            x[tb + 7 + 2 * lane], x[tb + 8 + 2 * lane],
                            x[tb + 3 + lane]);
    llacc += llb;
    WAVE_FENCE();
    if (lane == 0)
        llacc += fused_step_ip(acol, sBT, &sB6[u][0][0], 0,
                               x[tb + 1], x[tb + 2], x[tb + 0]);

    #pragma unroll
    for (int off = 32; off; off >>= 1) llacc += __shfl_down(llacc, off);
    if (lane == 0) out[tree * NGEN + g] = llacc;
}

extern "C" void kernel_launch(void* const* d_in, const int* in_sizes, int n_in,
                              void* d_out, int out_size, void* d_ws, size_t ws_size,
                              hipStream_t stream) {
    const int*   x  = (const int*)d_in[0];
    const float* A  = (const float*)d_in[1];
    const float* B  = (const float*)d_in[2];
    const float* Pi = (const float*)d_in[3];
    float* out = (float*)d_out;

    if (ws_size >= (size_t)WS_FLOATS * sizeof(float)) {
        float* ws = (float*)d_ws;
        htmm_setup<<<NGEN, 128, 0, stream>>>(A, B, Pi, ws);
        htmm_main<<<NTREES * NGEN, 64, 0, stream>>>(x, ws, out);
    } else {
        htmm_fused<<<NTREES, 256, 0, stream>>>(x, A, B, Pi, out);
    }
}

// Round 16
// 26.188 us; speedup vs baseline: 1.4586x; 1.4586x over previous
//
#include <hip/hip_runtime.h>
#include <math.h>

#define NC     10
#define NCP    12     // padded row stride (floats); 48B rows, 16B aligned
#define NM     128
#define NGEN   4
#define NPT    1023
#define NTREES 1024

#define RCPF(x) __builtin_amdgcn_rcpf(x)
#define WAVE_FENCE() __builtin_amdgcn_wave_barrier()

struct F12 { float4 a, b, c; };

__device__ __forceinline__ F12 ld12(const float* p) {
    F12 r; const float4* q = (const float4*)p;
    r.a = q[0]; r.b = q[1]; r.c = q[2]; return r;
}
__device__ __forceinline__ void unpack10(float* t, const F12& r) {
    t[0] = r.a.x; t[1] = r.a.y; t[2] = r.a.z; t[3] = r.a.w;
    t[4] = r.b.x; t[5] = r.b.y; t[6] = r.b.z; t[7] = r.b.w;
    t[8] = r.c.x; t[9] = r.c.y;
}
__device__ __forceinline__ void fma10(float* t, const F12& c, float s) {
    t[0] += c.a.x * s; t[1] += c.a.y * s; t[2] += c.a.z * s; t[3] += c.a.w * s;
    t[4] += c.b.x * s; t[5] += c.b.y * s; t[6] += c.b.z * s; t[7] += c.b.w * s;
    t[8] += c.c.x * s; t[9] += c.c.y * s;
}
__device__ __forceinline__ void mul10(float* t, const F12& r) {
    t[0] *= r.a.x; t[1] *= r.a.y; t[2] *= r.a.z; t[3] *= r.a.w;
    t[4] *= r.b.x; t[5] *= r.b.y; t[6] *= r.b.z; t[7] *= r.b.w;
    t[8] *= r.c.x; t[9] *= r.c.y;
}
__device__ __forceinline__ float sum10(const float* v) {
    return (((v[0] + v[1]) + (v[2] + v[3])) + ((v[4] + v[5]) + (v[6] + v[7]))) + (v[8] + v[9]);
}

// 7-node telescoped half-subtree {4 leaves, 2 L8 unnorm, L7}: 1 log + 1 rcp.
// Leaves read the pi-prefolded sBTpi table (keeps piv out of registers).
__device__ __forceinline__ float half_subtree(const F12* acol,
                                              const float (*sBT)[NCP],
                                              const float (*sBTpi)[NCP],
                                              int xl0, int xl1, int xl2, int xl3,
                                              int x8a, int x8b, int x7, float* b7out)
{
    float b0[NC], b1[NC], sc[NC], t8a[NC], t8b[NC];

    unpack10(b0, ld12(&sBTpi[xl0][0]));
    unpack10(b1, ld12(&sBTpi[xl1][0]));
    float nu0 = sum10(b0), nu1 = sum10(b1);
    #pragma unroll
    for (int j = 0; j < NC; ++j) sc[j] = b0[j] * nu1 + b1[j] * nu0;
    #pragma unroll
    for (int i = 0; i < NC; ++i) t8a[i] = 0.f;
    #pragma unroll
    for (int j = 0; j < NC; ++j) fma10(t8a, acol[j], sc[j]);
    mul10(t8a, ld12(&sBT[x8a][0]));
    const float nu8a = sum10(t8a);

    unpack10(b0, ld12(&sBTpi[xl2][0]));
    unpack10(b1, ld12(&sBTpi[xl3][0]));
    nu0 = sum10(b0); nu1 = sum10(b1);
    #pragma unroll
    for (int j = 0; j < NC; ++j) sc[j] = b0[j] * nu1 + b1[j] * nu0;
    #pragma unroll
    for (int i = 0; i < NC; ++i) t8b[i] = 0.f;
    #pragma unroll
    for (int j = 0; j < NC; ++j) fma10(t8b, acol[j], sc[j]);
    mul10(t8b, ld12(&sBT[x8b][0]));
    const float nu8b = sum10(t8b);

    #pragma unroll
    for (int j = 0; j < NC; ++j) sc[j] = t8a[j] * nu8b + t8b[j] * nu8a;
    float t7[NC];
    #pragma unroll
    for (int i = 0; i < NC; ++i) t7[i] = 0.f;
    #pragma unroll
    for (int j = 0; j < NC; ++j) fma10(t7, acol[j], sc[j]);
    mul10(t7, ld12(&sBT[x7][0]));
    const float nu7 = sum10(t7);
    const float r = RCPF(nu7);
    #pragma unroll
    for (int j = 0; j < NC; ++j) b7out[j] = t7[j] * r;
    return __logf(nu7);
}

// fused 2-level tail step, in place (stride 64), telescoped (1 log, 1 rcp).
__device__ __forceinline__ float fused_step_ip(const F12* acol, const float (*sBT)[NCP],
                                               float* buf, int l,
                                               int xc0, int xc1, int xp)
{
    float t0[NC], t1[NC];
    #pragma unroll
    for (int i = 0; i < NC; ++i) { t0[i] = 0.f; t1[i] = 0.f; }
    #pragma unroll
    for (int j = 0; j < NC; ++j) {
        float4 gv = *(const float4*)(buf + j * 64 + 4 * l);
        fma10(t0, acol[j], gv.x + gv.y);
        fma10(t1, acol[j], gv.z + gv.w);
    }
    mul10(t0, ld12(&sBT[xc0][0]));
    mul10(t1, ld12(&sBT[xc1][0]));
    const float nu0 = sum10(t0), nu1 = sum10(t1);
    float tp[NC];
    #pragma unroll
    for (int i = 0; i < NC; ++i) tp[i] = 0.f;
    #pragma unroll
    for (int j = 0; j < NC; ++j) fma10(tp, acol[j], t0[j] * nu1 + t1[j] * nu0);
    mul10(tp, ld12(&sBT[xp][0]));
    const float nup = sum10(tp);
    const float rp = RCPF(nup);
    #pragma unroll
    for (int j = 0; j < NC; ++j) buf[j * 64 + l] = tp[j] * rp;
    return __logf(nup);
}

// ---------------- single fused kernel ----------------
// block = 256 threads = 4 (tree,g) units (one wave each, same g per block).
// Lane = one L6 subtree SEQUENTIALLY in registers; A in 30 VGPRs.
// __launch_bounds__(256, 2): cap VGPR at EXACTLY the 128 tier (4 waves/SIMD).
// R13 measured 136 VGPR -> 2 waves/SIMD -> 41 µs; this guards that cliff.
// (R7's catastrophic spill was the (256,4) -> 64-VGPR cap; 128 is safe.)
// Pi is prefolded into the sBTpi LDS table (R11-style) so piv[10] does NOT
// stay live across the head — lower peak VGPR than R14's per-thread piv.
__global__ __launch_bounds__(256, 2)
void htmm_fused(const int* __restrict__ x,
                const float* __restrict__ A,
                const float* __restrict__ B,
                const float* __restrict__ Pi,
                float* __restrict__ out)
{
    __shared__ __align__(16) float sACol[NC][NCP];   // 0.5*smA[i][j], col-major
    __shared__ __align__(16) float sBT[NM][NCP];     // smB^T rows
    __shared__ __align__(16) float sBTpi[NM][NCP];   // pi (.) smB^T rows (leaves)
    __shared__ __align__(16) float sPiP[NCP];
    __shared__ __align__(16) float sB6[4][NC][64];   // per-unit SoA; tail in place

    const int bid = blockIdx.x;
    const int g = bid >> 8;
    const int treeBase = (bid & 255) * 4;
    const int tid = threadIdx.x;
    const int u = tid >> 6, lane = tid & 63;

    const int tree = treeBase + u;
    const int tb = tree * NPT;

    // ---- hoisted observation-index loads (overlap setup latency) ----
    int xl[8];
    #pragma unroll
    for (int k = 0; k < 8; ++k) xl[k] = x[tb + 511 + 8 * lane + k];
    int x8v[4];
    #pragma unroll
    for (int c = 0; c < 4; ++c) x8v[c] = x[tb + 255 + 4 * lane + c];
    const int x7a = x[tb + 127 + 2 * lane];
    const int x7b = x[tb + 128 + 2 * lane];
    const int x6v = x[tb + 63 + lane];

    // ---- parameter softmaxes (B: no-max — |2.5*N| small, exp safe; R11-validated) ----
    for (int c = u; c < NC; c += 4) {
        float e0 = __expf(B[(c * NM + lane) * NGEN + g]);
        float e1 = __expf(B[(c * NM + lane + 64) * NGEN + g]);
        float sm = e0 + e1;
        #pragma unroll
        for (int off = 32; off; off >>= 1) sm += __shfl_xor(sm, off);
        const float rs = 1.f / sm;
        sBT[lane][c]      = e0 * rs;
        sBT[lane + 64][c] = e1 * rs;
    }
    if (tid >= 128 && tid < 128 + NC) {   // A column softmax on wave 2
        const int j = tid - 128;
        float col[NC], mx = -1e30f;
        #pragma unroll
        for (int i = 0; i < NC; ++i) { col[i] = A[(i * NC + j) * NGEN + g]; mx = fmaxf(mx, col[i]); }
        float sm = 0.f;
        #pragma unroll
        for (int i = 0; i < NC; ++i) { col[i] = __expf(col[i] - mx); sm += col[i]; }
        const float rs = 0.5f / sm;
        #pragma unroll
        for (int i = 0; i < NC; ++i) sACol[j][i] = col[i] * rs;
    }
    if (tid == 192) {                     // Pi softmax on wave 3
        float col[NC], mx = -1e30f;
        #pragma unroll
        for (int i = 0; i < NC; ++i) { col[i] = Pi[i * NGEN + g]; mx = fmaxf(mx, col[i]); }
        float sm = 0.f;
        #pragma unroll
        for (int i = 0; i < NC; ++i) { col[i] = __expf(col[i] - mx); sm += col[i]; }
        const float rs = 1.f / sm;
        #pragma unroll
        for (int i = 0; i < NC; ++i) sPiP[i] = col[i] * rs;
    }
    __syncthreads();
    if (tid < NM) {   // sBTpi[m][c] = pi[c] * sBT[m][c]  (piv never lives in head regs)
        F12 pi = ld12(sPiP);
        F12 r  = ld12(&sBT[tid][0]);
        sBTpi[tid][0] = pi.a.x * r.a.x; sBTpi[tid][1] = pi.a.y * r.a.y;
        sBTpi[tid][2] = pi.a.z * r.a.z; sBTpi[tid][3] = pi.a.w * r.a.w;
        sBTpi[tid][4] = pi.b.x * r.b.x; sBTpi[tid][5] = pi.b.y * r.b.y;
        sBTpi[tid][6] = pi.b.z * r.b.z; sBTpi[tid][7] = pi.b.w * r.b.w;
        sBTpi[tid][8] = pi.c.x * r.c.x; sBTpi[tid][9] = pi.c.y * r.c.y;
    }
    __syncthreads();

    // ---- hoist A into registers (one-time broadcast reads) ----
    F12 acol[NC];
    #pragma unroll
    for (int j = 0; j < NC; ++j) acol[j] = ld12(&sACol[j][0]);

    // ---- head: two telescoped halves, then L6 ----
    float b7a[NC], b7b[NC];
    float llacc;
    llacc  = half_subtree(acol, sBT, sBTpi, xl[0], xl[1], xl[2], xl[3],
                          x8v[0], x8v[1], x7a, b7a);
    llacc += half_subtree(acol, sBT, sBTpi, xl[4], xl[5], xl[6], xl[7],
                          x8v[2], x8v[3], x7b, b7b);

    {   // L6: one A-pass on (b7a + b7b)
        float sc[NC], t6[NC];
        #pragma unroll
        for (int j = 0; j < NC; ++j) sc[j] = b7a[j] + b7b[j];
        #pragma unroll
        for (int i = 0; i < NC; ++i) t6[i] = 0.f;
        #pragma unroll
        for (int j = 0; j < NC; ++j) fma10(t6, acol[j], sc[j]);
        mul10(t6, ld12(&sBT[x6v][0]));
        const float nup = sum10(t6);
        llacc += __logf(nup);
        const float rp = RCPF(nup);
        #pragma unroll
        for (int j = 0; j < NC; ++j) sB6[u][j][lane] = t6[j] * rp;
    }

    // ---- tail: levels 5..0, wave-local, in place in sB6 ----
    WAVE_FENCE();
    float lla = 0.f;
    if (lane < 16)
        lla = fused_step_ip(acol, sBT, &sB6[u][0][0], lane,
                            x[tb + 31 + 2 * lane], x[tb + 32 + 2 * lane],
                            x[tb + 15 + lane]);
    llacc += lla;
    WAVE_FENCE();
    float llb = 0.f;
    if (lane < 4)
        llb = fused_step_ip(acol, sBT, &sB6[u][0][0], lane,
                            x[tb + 7 + 2 * lane], x[tb + 8 + 2 * lane],
                            x[tb + 3 + lane]);
    llacc += llb;
    WAVE_FENCE();
    if (lane == 0)
        llacc += fused_step_ip(acol, sBT, &sB6[u][0][0], 0,
                               x[tb + 1], x[tb + 2], x[tb + 0]);

    // ---- full-wave reduce; lane 0 writes the unit's output ----
    #pragma unroll
    for (int off = 32; off; off >>= 1) llacc += __shfl_down(llacc, off);
    if (lane == 0) out[tree * NGEN + g] = llacc;
}

extern "C" void kernel_launch(void* const* d_in, const int* in_sizes, int n_in,
                              void* d_out, int out_size, void* d_ws, size_t ws_size,
                              hipStream_t stream) {
    const int*   x  = (const int*)d_in[0];
    const float* A  = (const float*)d_in[1];
    const float* B  = (const float*)d_in[2];
    const float* Pi = (const float*)d_in[3];
    float* out = (float*)d_out;
    htmm_fused<<<NTREES, 256, 0, stream>>>(x, A, B, Pi, out);
}

// Round 17
// 24.883 us; speedup vs baseline: 1.5351x; 1.0525x over previous
//
#include <hip/hip_runtime.h>
#include <math.h>

#define NC     10
#define NCP    12     // padded row stride (floats); 48B rows, 16B aligned
#define NM     128
#define NGEN   4
#define NPT    1023
#define NTREES 1024

#define RCPF(x) __builtin_amdgcn_rcpf(x)
#define WAVE_FENCE() __builtin_amdgcn_wave_barrier()

struct F12 { float4 a, b, c; };

__device__ __forceinline__ F12 ld12(const float* p) {
    F12 r; const float4* q = (const float4*)p;
    r.a = q[0]; r.b = q[1]; r.c = q[2]; return r;
}
__device__ __forceinline__ void unpack10(float* t, const F12& r) {
    t[0] = r.a.x; t[1] = r.a.y; t[2] = r.a.z; t[3] = r.a.w;
    t[4] = r.b.x; t[5] = r.b.y; t[6] = r.b.z; t[7] = r.b.w;
    t[8] = r.c.x; t[9] = r.c.y;
}
__device__ __forceinline__ void fma10(float* t, const F12& c, float s) {
    t[0] += c.a.x * s; t[1] += c.a.y * s; t[2] += c.a.z * s; t[3] += c.a.w * s;
    t[4] += c.b.x * s; t[5] += c.b.y * s; t[6] += c.b.z * s; t[7] += c.b.w * s;
    t[8] += c.c.x * s; t[9] += c.c.y * s;
}
__device__ __forceinline__ void mul10(float* t, const F12& r) {
    t[0] *= r.a.x; t[1] *= r.a.y; t[2] *= r.a.z; t[3] *= r.a.w;
    t[4] *= r.b.x; t[5] *= r.b.y; t[6] *= r.b.z; t[7] *= r.b.w;
    t[8] *= r.c.x; t[9] *= r.c.y;
}
__device__ __forceinline__ float sum10(const float* v) {
    return (((v[0] + v[1]) + (v[2] + v[3])) + ((v[4] + v[5]) + (v[6] + v[7]))) + (v[8] + v[9]);
}

// 7-node telescoped half-subtree {4 leaves, 2 L8 unnorm, L7}: 1 log + 1 rcp.
__device__ __forceinline__ float half_subtree(const F12* acol,
                                              const float (*sBT)[NCP],
                                              const float (*sBTpi)[NCP],
                                              int xl0, int xl1, int xl2, int xl3,
                                              int x8a, int x8b, int x7, float* b7out)
{
    float b0[NC], b1[NC], sc[NC], t8a[NC], t8b[NC];

    unpack10(b0, ld12(&sBTpi[xl0][0]));
    unpack10(b1, ld12(&sBTpi[xl1][0]));
    float nu0 = sum10(b0), nu1 = sum10(b1);
    #pragma unroll
    for (int j = 0; j < NC; ++j) sc[j] = b0[j] * nu1 + b1[j] * nu0;
    #pragma unroll
    for (int i = 0; i < NC; ++i) t8a[i] = 0.f;
    #pragma unroll
    for (int j = 0; j < NC; ++j) fma10(t8a, acol[j], sc[j]);
    mul10(t8a, ld12(&sBT[x8a][0]));
    const float nu8a = sum10(t8a);

    unpack10(b0, ld12(&sBTpi[xl2][0]));
    unpack10(b1, ld12(&sBTpi[xl3][0]));
    nu0 = sum10(b0); nu1 = sum10(b1);
    #pragma unroll
    for (int j = 0; j < NC; ++j) sc[j] = b0[j] * nu1 + b1[j] * nu0;
    #pragma unroll
    for (int i = 0; i < NC; ++i) t8b[i] = 0.f;
    #pragma unroll
    for (int j = 0; j < NC; ++j) fma10(t8b, acol[j], sc[j]);
    mul10(t8b, ld12(&sBT[x8b][0]));
    const float nu8b = sum10(t8b);

    #pragma unroll
    for (int j = 0; j < NC; ++j) sc[j] = t8a[j] * nu8b + t8b[j] * nu8a;
    float t7[NC];
    #pragma unroll
    for (int i = 0; i < NC; ++i) t7[i] = 0.f;
    #pragma unroll
    for (int j = 0; j < NC; ++j) fma10(t7, acol[j], sc[j]);
    mul10(t7, ld12(&sBT[x7][0]));
    const float nu7 = sum10(t7);
    const float r = RCPF(nu7);
    #pragma unroll
    for (int j = 0; j < NC; ++j) b7out[j] = t7[j] * r;
    return __logf(nu7);
}

// fused 2-level tail step, in place (stride 64), telescoped (1 log, 1 rcp).
__device__ __forceinline__ float fused_step_ip(const F12* acol, const float (*sBT)[NCP],
                                               float* buf, int l,
                                               int xc0, int xc1, int xp)
{
    float t0[NC], t1[NC];
    #pragma unroll
    for (int i = 0; i < NC; ++i) { t0[i] = 0.f; t1[i] = 0.f; }
    #pragma unroll
    for (int j = 0; j < NC; ++j) {
        float4 gv = *(const float4*)(buf + j * 64 + 4 * l);
        fma10(t0, acol[j], gv.x + gv.y);
        fma10(t1, acol[j], gv.z + gv.w);
    }
    mul10(t0, ld12(&sBT[xc0][0]));
    mul10(t1, ld12(&sBT[xc1][0]));
    const float nu0 = sum10(t0), nu1 = sum10(t1);
    float tp[NC];
    #pragma unroll
    for (int i = 0; i < NC; ++i) tp[i] = 0.f;
    #pragma unroll
    for (int j = 0; j < NC; ++j) fma10(tp, acol[j], t0[j] * nu1 + t1[j] * nu0);
    mul10(tp, ld12(&sBT[xp][0]));
    const float nup = sum10(tp);
    const float rp = RCPF(nup);
    #pragma unroll
    for (int j = 0; j < NC; ++j) buf[j * 64 + l] = tp[j] * rp;
    return __logf(nup);
}

// ---------------- single fused kernel ----------------
// block = 256 threads = 4 (tree,g) units (one wave each, same g per block).
// Head: lane = one L6 subtree, two 7-node telescoped halves + L6 (A in regs).
// TAIL CONSOLIDATION (new): after one barrier, waves 1-3 EXIT; wave 0 runs
// all 4 units' tails packed — stage A uses 64/64 lanes (4 units x 16 parents),
// stage B 16 lanes, stage C 4 lanes. Cuts block issue ~26% (tail was 38% of
// every wave's inst stream at <=25% lane utilization).
__global__ __launch_bounds__(256, 2)
void htmm_fused(const int* __restrict__ x,
                const float* __restrict__ A,
                const float* __restrict__ B,
                const float* __restrict__ Pi,
                float* __restrict__ out)
{
    __shared__ __align__(16) float sACol[NC][NCP];   // 0.5*smA[i][j], col-major
    __shared__ __align__(16) float sBT[NM][NCP];     // smB^T rows
    __shared__ __align__(16) float sBTpi[NM][NCP];   // pi (.) smB^T rows (leaves)
    __shared__ __align__(16) float sPiP[NCP];
    __shared__ __align__(16) float sB6[4][NC][64];   // per-unit SoA; tail in place
    __shared__ float sll[4];                          // per-unit ll accumulator

    const int bid = blockIdx.x;
    const int g = bid >> 8;
    const int treeBase = (bid & 255) * 4;
    const int tid = threadIdx.x;
    const int u = tid >> 6, lane = tid & 63;

    const int tree = treeBase + u;
    const int tb = tree * NPT;

    // ---- hoisted observation-index loads (overlap setup latency) ----
    int xl[8];
    #pragma unroll
    for (int k = 0; k < 8; ++k) xl[k] = x[tb + 511 + 8 * lane + k];
    int x8v[4];
    #pragma unroll
    for (int c = 0; c < 4; ++c) x8v[c] = x[tb + 255 + 4 * lane + c];
    const int x7a = x[tb + 127 + 2 * lane];
    const int x7b = x[tb + 128 + 2 * lane];
    const int x6v = x[tb + 63 + lane];

    // ---- parameter softmaxes (B: no-max — |2.5*N| small, exp safe) ----
    for (int c = u; c < NC; c += 4) {
        float e0 = __expf(B[(c * NM + lane) * NGEN + g]);
        float e1 = __expf(B[(c * NM + lane + 64) * NGEN + g]);
        float sm = e0 + e1;
        #pragma unroll
        for (int off = 32; off; off >>= 1) sm += __shfl_xor(sm, off);
        const float rs = 1.f / sm;
        sBT[lane][c]      = e0 * rs;
        sBT[lane + 64][c] = e1 * rs;
    }
    if (tid >= 128 && tid < 128 + NC) {   // A column softmax on wave 2
        const int j = tid - 128;
        float col[NC], mx = -1e30f;
        #pragma unroll
        for (int i = 0; i < NC; ++i) { col[i] = A[(i * NC + j) * NGEN + g]; mx = fmaxf(mx, col[i]); }
        float sm = 0.f;
        #pragma unroll
        for (int i = 0; i < NC; ++i) { col[i] = __expf(col[i] - mx); sm += col[i]; }
        const float rs = 0.5f / sm;
        #pragma unroll
        for (int i = 0; i < NC; ++i) sACol[j][i] = col[i] * rs;
    }
    if (tid == 192) {                     // Pi softmax on wave 3
        float col[NC], mx = -1e30f;
        #pragma unroll
        for (int i = 0; i < NC; ++i) { col[i] = Pi[i * NGEN + g]; mx = fmaxf(mx, col[i]); }
        float sm = 0.f;
        #pragma unroll
        for (int i = 0; i < NC; ++i) { col[i] = __expf(col[i] - mx); sm += col[i]; }
        const float rs = 1.f / sm;
        #pragma unroll
        for (int i = 0; i < NC; ++i) sPiP[i] = col[i] * rs;
    }
    __syncthreads();
    if (tid < NM) {   // sBTpi[m][c] = pi[c] * sBT[m][c]
        F12 pi = ld12(sPiP);
        F12 r  = ld12(&sBT[tid][0]);
        sBTpi[tid][0] = pi.a.x * r.a.x; sBTpi[tid][1] = pi.a.y * r.a.y;
        sBTpi[tid][2] = pi.a.z * r.a.z; sBTpi[tid][3] = pi.a.w * r.a.w;
        sBTpi[tid][4] = pi.b.x * r.b.x; sBTpi[tid][5] = pi.b.y * r.b.y;
        sBTpi[tid][6] = pi.b.z * r.b.z; sBTpi[tid][7] = pi.b.w * r.b.w;
        sBTpi[tid][8] = pi.c.x * r.c.x; sBTpi[tid][9] = pi.c.y * r.c.y;
    }
    __syncthreads();

    // ---- hoist A into registers (one-time broadcast reads) ----
    F12 acol[NC];
    #pragma unroll
    for (int j = 0; j < NC; ++j) acol[j] = ld12(&sACol[j][0]);

    // ---- head: two telescoped halves, then L6 ----
    float b7a[NC], b7b[NC];
    float llacc;
    llacc  = half_subtree(acol, sBT, sBTpi, xl[0], xl[1], xl[2], xl[3],
                          x8v[0], x8v[1], x7a, b7a);
    llacc += half_subtree(acol, sBT, sBTpi, xl[4], xl[5], xl[6], xl[7],
                          x8v[2], x8v[3], x7b, b7b);

    {   // L6: one A-pass on (b7a + b7b)
        float sc[NC], t6[NC];
        #pragma unroll
        for (int j = 0; j < NC; ++j) sc[j] = b7a[j] + b7b[j];
        #pragma unroll
        for (int i = 0; i < NC; ++i) t6[i] = 0.f;
        #pragma unroll
        for (int j = 0; j < NC; ++j) fma10(t6, acol[j], sc[j]);
        mul10(t6, ld12(&sBT[x6v][0]));
        const float nup = sum10(t6);
        llacc += __logf(nup);
        const float rp = RCPF(nup);
        #pragma unroll
        for (int j = 0; j < NC; ++j) sB6[u][j][lane] = t6[j] * rp;
    }

    // ---- deposit head ll; one barrier; waves 1-3 exit ----
    #pragma unroll
    for (int off = 32; off; off >>= 1) llacc += __shfl_down(llacc, off);
    if (lane == 0) sll[u] = llacc;
    __syncthreads();
    if (u != 0) return;

    // ---- wave 0: all 4 units' tails, packed ----
    // stage A: 64 lanes = 4 units x 16 parents (levels 5+4)
    {
        const int tu = lane >> 4, l = lane & 15;
        const int ttb = (treeBase + tu) * NPT;
        float lla = fused_step_ip(acol, sBT, &sB6[tu][0][0], l,
                                  x[ttb + 31 + 2 * l], x[ttb + 32 + 2 * l],
                                  x[ttb + 15 + l]);
        #pragma unroll
        for (int off = 8; off; off >>= 1) lla += __shfl_down(lla, off, 16);
        if (l == 0) sll[tu] += lla;
    }
    WAVE_FENCE();
    // stage B: 16 lanes = 4 units x 4 parents (levels 3+2)
    if (lane < 16) {
        const int tu = lane >> 2, l = lane & 3;
        const int ttb = (treeBase + tu) * NPT;
        float llb = fused_step_ip(acol, sBT, &sB6[tu][0][0], l,
                                  x[ttb + 7 + 2 * l], x[ttb + 8 + 2 * l],
                                  x[ttb + 3 + l]);
        #pragma unroll
        for (int off = 2; off; off >>= 1) llb += __shfl_down(llb, off, 4);
        if (l == 0) sll[tu] += llb;
    }
    WAVE_FENCE();
    // stage C: 4 lanes = 4 units x 1 (levels 1+0)
    if (lane < 4) {
        const int tu = lane;
        const int ttb = (treeBase + tu) * NPT;
        float llc = fused_step_ip(acol, sBT, &sB6[tu][0][0], 0,
                                  x[ttb + 1], x[ttb + 2], x[ttb + 0]);
        sll[tu] += llc;
    }
    WAVE_FENCE();
    if (lane < 4)
        out[(treeBase + lane) * NGEN + g] = sll[lane];
}

extern "C" void kernel_launch(void* const* d_in, const int* in_sizes, int n_in,
                              void* d_out, int out_size, void* d_ws, size_t ws_size,
                              hipStream_t stream) {
    const int*   x  = (const int*)d_in[0];
    const float* A  = (const float*)d_in[1];
    const float* B  = (const float*)d_in[2];
    const float* Pi = (const float*)d_in[3];
    float* out = (float*)d_out;
    htmm_fused<<<NTREES, 256, 0, stream>>>(x, A, B, Pi, out);
}